// Round 10
// baseline (7384.360 us; speedup 1.0000x reference)
//
#include <hip/hip_runtime.h>
#include <hip/hip_bf16.h>
#include <stdint.h>
#include <stddef.h>

// ---------------- problem dims (fixed by setup_inputs) ----------------
#define M_DIM 8192
#define K_DIM 4096
#define N_DIM 16384

#define BM 256
#define BN 256
#define BK 32
#define KSTEPS (K_DIM / BK)     // 128
#define SLOT_SH (BM * BK)       // 8192 shorts = 16 KB per matrix per slot

typedef __attribute__((ext_vector_type(8))) short bf16x8;  // 8 bf16 = 4 VGPRs
typedef __attribute__((ext_vector_type(4))) float f32x4;
typedef __attribute__((ext_vector_type(4))) int   i32x4;

// fp32 -> bf16, round-to-nearest-even (inputs finite)
static __device__ __forceinline__ short f2bf(float f) {
    union { float f; uint32_t u; } v; v.f = f;
    uint32_t r = v.u + 0x7FFFu + ((v.u >> 16) & 1u);
    return (short)(r >> 16);
}

// FP4 E2M1 decode: low 3 bits magnitude code, bit 3 sign.
static __device__ __forceinline__ float e2m1(int v) {
    int e = (v >> 1) & 3;
    int m = v & 1;
    float mag = (e == 0) ? 0.5f * (float)m
                         : (float)(2 + m) * 0.25f * (float)(1 << e);
    return (v & 8) ? -mag : mag;
}

// async global->LDS, 16 bytes per lane; LDS dest is wave-uniform base + lane*16
static __device__ __forceinline__ void gload16(short* lds, const short* g) {
    __builtin_amdgcn_global_load_lds(
        (const __attribute__((address_space(1))) void*)g,
        (__attribute__((address_space(3))) void*)lds,
        16, 0, 0);
}

// ---------------- kernel 1: x fp32 -> bf16 ----------------
__global__ void cast_x_kernel(const float* __restrict__ x, short* __restrict__ xb) {
    size_t i = (size_t)blockIdx.x * 256 + threadIdx.x;   // one short8 per thread
    const float4* s = reinterpret_cast<const float4*>(x);
    float4 a = s[2 * i];
    float4 b = s[2 * i + 1];
    bf16x8 o;
    o[0] = f2bf(a.x); o[1] = f2bf(a.y); o[2] = f2bf(a.z); o[3] = f2bf(a.w);
    o[4] = f2bf(b.x); o[5] = f2bf(b.y); o[6] = f2bf(b.z); o[7] = f2bf(b.w);
    reinterpret_cast<bf16x8*>(xb)[i] = o;
}

// ---------------- kernel 2: dequant w_q -> bf16 [N, K] ----------------
__global__ void dequant_w_kernel(const int* __restrict__ wq,
                                 const float* __restrict__ wos,
                                 const float* __restrict__ wis,
                                 short* __restrict__ wb) {
    int tid = blockIdx.x * 256 + threadIdx.x;    // N*(K/16) = 4,194,304 total
    int n   = tid >> 8;                          // K/16 = 256 inner blocks per row
    int blk = tid & 255;
    float scale = wis[(n << 8) | blk] * wos[(n << 5) | (blk >> 3)];
    const i32x4* q = reinterpret_cast<const i32x4*>(wq + ((size_t)n << 11) + (blk << 3));
    i32x4 q0 = q[0], q1 = q[1];
    bf16x8 o0, o1;
#pragma unroll
    for (int j = 0; j < 4; ++j) {
        int c = q0[j];
        o0[2 * j]     = f2bf(e2m1(c & 15) * scale);         // even in-feature
        o0[2 * j + 1] = f2bf(e2m1((c >> 4) & 15) * scale);  // odd in-feature
    }
#pragma unroll
    for (int j = 0; j < 4; ++j) {
        int c = q1[j];
        o1[2 * j]     = f2bf(e2m1(c & 15) * scale);
        o1[2 * j + 1] = f2bf(e2m1((c >> 4) & 15) * scale);
    }
    bf16x8* dst = reinterpret_cast<bf16x8*>(wb) + 2 * (size_t)tid;
    dst[0] = o0;
    dst[1] = o1;
}

// ---------------- kernel 3: C[M,N] = A[M,K] * B[N,K]^T, bf16 in / fp32 out --
// R9: R7's phase ordering + 2 BLOCKS/CU (the missing overlap source).
// Pipe ledger per CU per K-step: MFMA 1242 cyc (matrix pipe) vs ds_read 1152
// + LDS-write 256 (DS pipe). R7/R8 measured ~2900-3200 cyc/K-step = the
// SERIALIZED sum: with 1 block/CU every wave shares the same barriers, so DS
// windows and MFMA windows occupy disjoint time slots. Two co-resident
// blocks share no barrier -> one block's DS/gate windows overlap the other's
// MFMA clusters (m114 implicit overlap; m97's 912 TF came from ~3 blk/CU).
//   - 256x256 tile, BK=32, 512 thr (8 waves, 2m x 4n; 128x64 C per wave)
//   - 2-slot rings for A and B: LDS 64 KB/block -> 2 blocks/CU (128<=160 KB)
//   - __launch_bounds__(512,4): 4 waves/SIMD min => 2 blocks/CU
//   - ph0: reads(tile tt: B + A m0-3) + STAGE_B(tt+1) -> gate -> MFMA Q0
//   - ph1: reads(A m4-7) + STAGE_A(tt+1) -> gate -> MFMA Q1 -> vmcnt(0) -> bar
//     (vmcnt(0) drains loads issued 0.5-1.5 phases earlier, L2-hit mostly
//      landed; residual covered by the co-resident block's compute)
// Swizzle (R4-verified conflict-free), raster (R3-verified FETCH), epilogue
// unchanged. Race audit: stage writes slot (tt+1)&1 != read slot tt&1; all
// staged data drained by vmcnt(0)+barrier before next step's reads.
__global__ __launch_bounds__(512, 4)
void gemm_bt_kernel(const short* __restrict__ A,
                    const short* __restrict__ B,
                    float* __restrict__ C) {
    __shared__ __align__(16) short As[2 * SLOT_SH];   // 32 KB
    __shared__ __align__(16) short Bs[2 * SLOT_SH];   // 32 KB

    // raster: each XCD owns an 8-wide n-stripe, n-fast (R3, FETCH-verified)
    int bid = blockIdx.x;
    int xcd = bid & 7;
    int idx = bid >> 3;          // 0..255
    int im  = idx >> 3;          // 0..31
    int in8 = idx & 7;           // 0..7
    int bm  = im << 8;
    int bn  = ((xcd << 3) + in8) << 8;

    int t    = threadIdx.x;
    int lane = t & 63;
    int w    = t >> 6;           // wave 0..7
    int wm   = w >> 2;           // 0..1
    int wn   = w & 3;            // 0..3
    int fr   = lane & 15;
    int fq   = lane >> 4;
    int wbase = w << 9;          // wave staging base (shorts): w * 512

    // staging: thread t covers row (t>>2) of each 128-row chunk, 16B slot t&3.
    // pre-swizzled global k-chunk = (t&3) ^ ((row>>1)&3)  (R4-verified)
    int gcol = (((t & 3) ^ ((t >> 3) & 3)) << 3);        // shorts
    const short* AgB = A + (size_t)(bm + (t >> 2)) * K_DIM + gcol;
    const short* BgB = B + (size_t)(bn + (t >> 2)) * K_DIM + gcol;

    // read-side swizzled slot (constant per lane): fq ^ ((fr>>1)&3)
    int slot = fq ^ ((fr >> 1) & 3);
    int aoff[8], boff[4];
#pragma unroll
    for (int mi = 0; mi < 8; ++mi)
        aoff[mi] = ((wm << 7) + mi * 16 + fr) * 4 + slot;
#pragma unroll
    for (int ni = 0; ni < 4; ++ni)
        boff[ni] = ((wn << 6) + ni * 16 + fr) * 4 + slot;

    f32x4 acc[8][4] = {};

    // one matrix K-step tile = 16 KB = 2 gloads (512 thr x 16 B = 8 KB each)
#define STAGE_A(slot_, kt_)                                                   \
    do {                                                                      \
        const short* _s = AgB + (size_t)(kt_) * BK;                           \
        short* _d = As + (slot_) * SLOT_SH + wbase;                           \
        gload16(_d,        _s);                                               \
        gload16(_d + 4096, _s + (size_t)128 * K_DIM);                         \
    } while (0)
#define STAGE_B(slot_, kt_)                                                   \
    do {                                                                      \
        const short* _s = BgB + (size_t)(kt_) * BK;                           \
        short* _d = Bs + (slot_) * SLOT_SH + wbase;                           \
        gload16(_d,        _s);                                               \
        gload16(_d + 4096, _s + (size_t)128 * K_DIM);                         \
    } while (0)

// phase boundary: pin reads/stage above, then barrier, then drain LDS and
// pin again so MFMA can't hoist past the wait (rule #18)
#define PHASE_GATE()                                                          \
    do {                                                                      \
        __builtin_amdgcn_sched_barrier(0);                                    \
        __builtin_amdgcn_s_barrier();                                         \
        asm volatile("s_waitcnt lgkmcnt(0)" ::: "memory");                    \
        __builtin_amdgcn_sched_barrier(0);                                    \
    } while (0)

    // prologue: stage K-step 0, drain, sync
    STAGE_A(0, 0);
    STAGE_B(0, 0);
    asm volatile("s_waitcnt vmcnt(0)" ::: "memory");
    __builtin_amdgcn_s_barrier();

    for (int tt = 0; tt < KSTEPS; ++tt) {
        int c     = tt & 1;
        int nslot = c ^ 1;
        int ktn   = (tt + 1) & (KSTEPS - 1);   // dead wrap at tt = 127
        const bf16x8* Af = reinterpret_cast<const bf16x8*>(As + c * SLOT_SH);
        const bf16x8* Bf = reinterpret_cast<const bf16x8*>(Bs + c * SLOT_SH);

        bf16x8 av[4], aw[4], bv[4];

        // ---- ph0: reads B + A m0-3; stage B(tt+1); gate; MFMA Q0
#pragma unroll
        for (int ni = 0; ni < 4; ++ni) bv[ni] = Bf[boff[ni]];
#pragma unroll
        for (int mi = 0; mi < 4; ++mi) av[mi] = Af[aoff[mi]];
        STAGE_B(nslot, ktn);
        PHASE_GATE();
        __builtin_amdgcn_s_setprio(1);
#pragma unroll
        for (int mi = 0; mi < 4; ++mi)
#pragma unroll
            for (int ni = 0; ni < 4; ++ni)
                acc[mi][ni] = __builtin_amdgcn_mfma_f32_16x16x32_bf16(
                    av[mi], bv[ni], acc[mi][ni], 0, 0, 0);
        __builtin_amdgcn_s_setprio(0);
        __builtin_amdgcn_s_barrier();

        // ---- ph1: reads A m4-7; stage A(tt+1); gate; MFMA Q1 (bv reused);
        //            end-of-step drain; closing barrier
#pragma unroll
        for (int mi = 0; mi < 4; ++mi) aw[mi] = Af[aoff[mi + 4]];
        STAGE_A(nslot, ktn);
        PHASE_GATE();
        __builtin_amdgcn_s_setprio(1);
#pragma unroll
        for (int mi = 0; mi < 4; ++mi)
#pragma unroll
            for (int ni = 0; ni < 4; ++ni)
                acc[mi + 4][ni] = __builtin_amdgcn_mfma_f32_16x16x32_bf16(
                    aw[mi], bv[ni], acc[mi + 4][ni], 0, 0, 0);
        __builtin_amdgcn_s_setprio(0);
        // drain tile tt+1 (B issued ~1.5 phases ago, A ~0.5); residual stall
        // is covered by the co-resident block's MFMA work.
        asm volatile("s_waitcnt vmcnt(0)" ::: "memory");
        __builtin_amdgcn_s_barrier();
    }
#undef PHASE_GATE
#undef STAGE_A
#undef STAGE_B

    // epilogue: C/D layout col = lane&15, row = (lane>>4)*4 + reg
#pragma unroll
    for (int mi = 0; mi < 8; ++mi) {
#pragma unroll
        for (int j = 0; j < 4; ++j) {
            size_t row = (size_t)(bm + (wm << 7) + mi * 16 + fq * 4 + j);
            float* Crow = C + row * N_DIM + (bn + (wn << 6) + fr);
#pragma unroll
            for (int ni = 0; ni < 4; ++ni)
                Crow[ni * 16] = acc[mi][ni][j];
        }
    }
}

// ---------------- launch ----------------
extern "C" void kernel_launch(void* const* d_in, const int* in_sizes, int n_in,
                              void* d_out, int out_size, void* d_ws, size_t ws_size,
                              hipStream_t stream) {
    const float* x   = (const float*)d_in[0];
    const int*   wq  = (const int*)d_in[1];
    const float* wos = (const float*)d_in[2];
    const float* wis = (const float*)d_in[3];
    float* out = (float*)d_out;

    short* xb = (short*)d_ws;                                        // 64 MB
    short* wb = (short*)((char*)d_ws + (size_t)M_DIM * K_DIM * 2);   // 128 MB

    cast_x_kernel<<<(M_DIM * (size_t)K_DIM / 8) / 256, 256, 0, stream>>>(x, xb);
    dequant_w_kernel<<<(N_DIM * (size_t)K_DIM / 16) / 256, 256, 0, stream>>>(wq, wos, wis, wb);
    gemm_bt_kernel<<<(M_DIM / BM) * (N_DIM / BN), 512, 0, stream>>>(xb, wb, out);
}

// Round 11
// 1178.765 us; speedup vs baseline: 6.2645x; 6.2645x over previous
//
#include <hip/hip_runtime.h>
#include <hip/hip_bf16.h>
#include <stdint.h>
#include <stddef.h>

// ---------------- problem dims (fixed by setup_inputs) ----------------
#define M_DIM 8192
#define K_DIM 4096
#define N_DIM 16384

#define BM 256
#define BN 256
#define BK 64
#define KT (K_DIM / BK)         // 64 K-tiles
#define SLOT_SH (BM * BK)       // 16384 shorts = 32 KB per matrix per slot

typedef __attribute__((ext_vector_type(8))) short bf16x8;   // 8 bf16 = 4 VGPRs
typedef __attribute__((ext_vector_type(4))) float f32x4;
typedef __attribute__((ext_vector_type(16))) float f32x16;  // 32x32 acc frag
typedef __attribute__((ext_vector_type(4))) int   i32x4;

// fp32 -> bf16, round-to-nearest-even (inputs finite)
static __device__ __forceinline__ short f2bf(float f) {
    union { float f; uint32_t u; } v; v.f = f;
    uint32_t r = v.u + 0x7FFFu + ((v.u >> 16) & 1u);
    return (short)(r >> 16);
}

// FP4 E2M1 decode: low 3 bits magnitude code, bit 3 sign.
static __device__ __forceinline__ float e2m1(int v) {
    int e = (v >> 1) & 3;
    int m = v & 1;
    float mag = (e == 0) ? 0.5f * (float)m
                         : (float)(2 + m) * 0.25f * (float)(1 << e);
    return (v & 8) ? -mag : mag;
}

// async global->LDS, 16 bytes per lane; LDS dest is wave-uniform base + lane*16
static __device__ __forceinline__ void gload16(short* lds, const short* g) {
    __builtin_amdgcn_global_load_lds(
        (const __attribute__((address_space(1))) void*)g,
        (__attribute__((address_space(3))) void*)lds,
        16, 0, 0);
}

// ---------------- kernel 1: x fp32 -> bf16 ----------------
__global__ void cast_x_kernel(const float* __restrict__ x, short* __restrict__ xb) {
    size_t i = (size_t)blockIdx.x * 256 + threadIdx.x;   // one short8 per thread
    const float4* s = reinterpret_cast<const float4*>(x);
    float4 a = s[2 * i];
    float4 b = s[2 * i + 1];
    bf16x8 o;
    o[0] = f2bf(a.x); o[1] = f2bf(a.y); o[2] = f2bf(a.z); o[3] = f2bf(a.w);
    o[4] = f2bf(b.x); o[5] = f2bf(b.y); o[6] = f2bf(b.z); o[7] = f2bf(b.w);
    reinterpret_cast<bf16x8*>(xb)[i] = o;
}

// ---------------- kernel 2: dequant w_q -> bf16 [N, K] ----------------
__global__ void dequant_w_kernel(const int* __restrict__ wq,
                                 const float* __restrict__ wos,
                                 const float* __restrict__ wis,
                                 short* __restrict__ wb) {
    int tid = blockIdx.x * 256 + threadIdx.x;    // N*(K/16) = 4,194,304 total
    int n   = tid >> 8;                          // K/16 = 256 inner blocks per row
    int blk = tid & 255;
    float scale = wis[(n << 8) | blk] * wos[(n << 5) | (blk >> 3)];
    const i32x4* q = reinterpret_cast<const i32x4*>(wq + ((size_t)n << 11) + (blk << 3));
    i32x4 q0 = q[0], q1 = q[1];
    bf16x8 o0, o1;
#pragma unroll
    for (int j = 0; j < 4; ++j) {
        int c = q0[j];
        o0[2 * j]     = f2bf(e2m1(c & 15) * scale);         // even in-feature
        o0[2 * j + 1] = f2bf(e2m1((c >> 4) & 15) * scale);  // odd in-feature
    }
#pragma unroll
    for (int j = 0; j < 4; ++j) {
        int c = q1[j];
        o1[2 * j]     = f2bf(e2m1(c & 15) * scale);
        o1[2 * j + 1] = f2bf(e2m1((c >> 4) & 15) * scale);
    }
    bf16x8* dst = reinterpret_cast<bf16x8*>(wb) + 2 * (size_t)tid;
    dst[0] = o0;
    dst[1] = o1;
}

// ---------------- kernel 3: C[M,N] = A[M,K] * B[N,K]^T, bf16 in / fp32 out --
// R10: R7 skeleton (best measured: 900 TF) with mfma_f32_32x32x16_bf16.
//   Mechanism: 32x32 matrix pipe is ~15% faster at peak (m119 2495 vs 2176
//   TF); half the MFMA instrs (32 vs 64 per wave-K-tile); half the barrier
//   pairs (2 phases of 16 MFMA instead of 4). Same LDS traffic & swizzle.
//   8 waves (2m x 4n), per-wave 128x64 C = 4 m-frags x 2 n-frags (32x32),
//   acc = 8 x f32x16 = 128 regs. NO min-waves in launch_bounds (R9 spilled
//   acc to scratch with (512,4): VGPR=64, 21.7 GB scratch writes).
//   Fragment layouts: A row = lane&31, k-run = (lane>>5)*8 (analogue of the
//   verified 16x16x32 mapping); C/D col = lane&31, row = (reg&3)+8*(reg>>2)
//   +4*(lane>>5) [m74/m101-verified]. Swizzle: LDS[row][s] holds global
//   chunk s^(row&7); read chunk(ksub,hi) = ksub*2+hi at slot chunk^(row&7).
//   Per phase: {12 ds_read + 4 gloads BEFORE barrier -> s_barrier ->
//   lgkmcnt(0) -> sched_barrier (rule #18) -> setprio(1) 16 MFMA setprio(0)
//   -> barrier}; vmcnt(0) once per K-tile at end of ph1 (R7 pattern; R8's
//   counted variant measured slower).
__global__ __launch_bounds__(512)
void gemm_bt_kernel(const short* __restrict__ A,
                    const short* __restrict__ B,
                    float* __restrict__ C) {
    __shared__ __align__(16) short As[2 * SLOT_SH];   // 64 KB
    __shared__ __align__(16) short Bs[2 * SLOT_SH];   // 64 KB

    // raster: each XCD owns an 8-wide n-stripe, n-fast (R3, FETCH-verified)
    int bid = blockIdx.x;
    int xcd = bid & 7;
    int idx = bid >> 3;          // 0..255
    int im  = idx >> 3;          // 0..31
    int in8 = idx & 7;           // 0..7
    int bm  = im << 8;
    int bn  = ((xcd << 3) + in8) << 8;

    int t    = threadIdx.x;
    int lane = t & 63;
    int w    = t >> 6;           // wave 0..7
    int wm   = w >> 2;           // 0..1
    int wn   = w & 3;            // 0..3
    int r31  = lane & 31;
    int hi   = lane >> 5;        // k-half within a 32x32x16 fragment
    int wbase = w << 9;          // wave staging base (shorts): w * 512

    // staging: thread t covers row (t>>3) of each 64-row chunk, 16B slot t&7.
    // pre-swizzled global k-chunk = (t&7) ^ (row&7)   (R6/R7-verified)
    int gcol = (((t & 7) ^ ((t >> 3) & 7)) << 3);        // shorts
    const short* AgB = A + (size_t)(bm + (t >> 3)) * K_DIM + gcol;
    const short* BgB = B + (size_t)(bn + (t >> 3)) * K_DIM + gcol;

    // read-side swizzled slots for the 4 ksubs (chunk = ksub*2 + hi)
    int sl[4];
#pragma unroll
    for (int ks = 0; ks < 4; ++ks) sl[ks] = (ks * 2 + hi) ^ (r31 & 7);
    // row bases in bf16x8 units (8 slots per row)
    int rowA[4], rowB[2];
#pragma unroll
    for (int mi = 0; mi < 4; ++mi) rowA[mi] = ((wm << 7) + mi * 32 + r31) * 8;
#pragma unroll
    for (int ni = 0; ni < 2; ++ni) rowB[ni] = ((wn << 6) + ni * 32 + r31) * 8;

    f32x16 acc[4][2] = {};

    // stage one 256-row matrix K-tile = 4 chunks of 64 rows (4 gloads/thread)
#define STAGE_A(slot_, kt_)                                                   \
    do {                                                                      \
        const short* _s = AgB + (size_t)(kt_) * BK;                           \
        short* _d = As + (slot_) * SLOT_SH + wbase;                           \
        gload16(_d,         _s);                                              \
        gload16(_d + 4096,  _s + (size_t)64  * K_DIM);                        \
        gload16(_d + 8192,  _s + (size_t)128 * K_DIM);                        \
        gload16(_d + 12288, _s + (size_t)192 * K_DIM);                        \
    } while (0)
#define STAGE_B(slot_, kt_)                                                   \
    do {                                                                      \
        const short* _s = BgB + (size_t)(kt_) * BK;                           \
        short* _d = Bs + (slot_) * SLOT_SH + wbase;                           \
        gload16(_d,         _s);                                              \
        gload16(_d + 4096,  _s + (size_t)64  * K_DIM);                        \
        gload16(_d + 8192,  _s + (size_t)128 * K_DIM);                        \
        gload16(_d + 12288, _s + (size_t)192 * K_DIM);                        \
    } while (0)

// phase boundary: pin reads/stage above, then barrier, then drain LDS and
// pin again so MFMA can't hoist past the wait (rule #18)
#define PHASE_GATE()                                                          \
    do {                                                                      \
        __builtin_amdgcn_sched_barrier(0);                                    \
        __builtin_amdgcn_s_barrier();                                         \
        asm volatile("s_waitcnt lgkmcnt(0)" ::: "memory");                    \
        __builtin_amdgcn_sched_barrier(0);                                    \
    } while (0)

    // prologue: stage K-tile 0, drain, sync
    STAGE_A(0, 0);
    STAGE_B(0, 0);
    asm volatile("s_waitcnt vmcnt(0)" ::: "memory");
    __builtin_amdgcn_s_barrier();

    for (int kt = 0; kt < KT; ++kt) {
        int c     = kt & 1;
        int nslot = c ^ 1;
        int ktn   = (kt + 1) & (KT - 1);   // dead wrap at kt = KT-1
        const bf16x8* Af = reinterpret_cast<const bf16x8*>(As + c * SLOT_SH);
        const bf16x8* Bf = reinterpret_cast<const bf16x8*>(Bs + c * SLOT_SH);

        bf16x8 av[4][2], bv[2][2];

        // ---- ph0: k 0..31 (ksub 0,1): 12 reads; stage A(kt+1); gate; 16 MFMA
#pragma unroll
        for (int ni = 0; ni < 2; ++ni) {
            bv[ni][0] = Bf[rowB[ni] + sl[0]];
            bv[ni][1] = Bf[rowB[ni] + sl[1]];
        }
#pragma unroll
        for (int mi = 0; mi < 4; ++mi) {
            av[mi][0] = Af[rowA[mi] + sl[0]];
            av[mi][1] = Af[rowA[mi] + sl[1]];
        }
        STAGE_A(nslot, ktn);
        PHASE_GATE();
        __builtin_amdgcn_s_setprio(1);
#pragma unroll
        for (int mi = 0; mi < 4; ++mi)
#pragma unroll
            for (int ni = 0; ni < 2; ++ni) {
                acc[mi][ni] = __builtin_amdgcn_mfma_f32_32x32x16_bf16(
                    av[mi][0], bv[ni][0], acc[mi][ni], 0, 0, 0);
                acc[mi][ni] = __builtin_amdgcn_mfma_f32_32x32x16_bf16(
                    av[mi][1], bv[ni][1], acc[mi][ni], 0, 0, 0);
            }
        __builtin_amdgcn_s_setprio(0);
        __builtin_amdgcn_s_barrier();

        // ---- ph1: k 32..63 (ksub 2,3): 12 reads; stage B(kt+1); gate;
        //           16 MFMA; end-of-K-tile drain; closing barrier
#pragma unroll
        for (int ni = 0; ni < 2; ++ni) {
            bv[ni][0] = Bf[rowB[ni] + sl[2]];
            bv[ni][1] = Bf[rowB[ni] + sl[3]];
        }
#pragma unroll
        for (int mi = 0; mi < 4; ++mi) {
            av[mi][0] = Af[rowA[mi] + sl[2]];
            av[mi][1] = Af[rowA[mi] + sl[3]];
        }
        STAGE_B(nslot, ktn);
        PHASE_GATE();
        __builtin_amdgcn_s_setprio(1);
#pragma unroll
        for (int mi = 0; mi < 4; ++mi)
#pragma unroll
            for (int ni = 0; ni < 2; ++ni) {
                acc[mi][ni] = __builtin_amdgcn_mfma_f32_32x32x16_bf16(
                    av[mi][0], bv[ni][0], acc[mi][ni], 0, 0, 0);
                acc[mi][ni] = __builtin_amdgcn_mfma_f32_32x32x16_bf16(
                    av[mi][1], bv[ni][1], acc[mi][ni], 0, 0, 0);
            }
        __builtin_amdgcn_s_setprio(0);
        asm volatile("s_waitcnt vmcnt(0)" ::: "memory");
        __builtin_amdgcn_s_barrier();
    }
#undef PHASE_GATE
#undef STAGE_A
#undef STAGE_B

    // epilogue: 32x32 C/D layout (m74/m101): col = lane&31,
    // row = (reg&3) + 8*(reg>>2) + 4*(lane>>5)
#pragma unroll
    for (int mi = 0; mi < 4; ++mi)
#pragma unroll
        for (int ni = 0; ni < 2; ++ni)
#pragma unroll
            for (int r = 0; r < 16; ++r) {
                size_t row = (size_t)(bm + (wm << 7) + mi * 32 +
                                      (r & 3) + 8 * (r >> 2) + 4 * hi);
                C[row * N_DIM + (bn + (wn << 6) + ni * 32 + r31)] = acc[mi][ni][r];
            }
}

// ---------------- launch ----------------
extern "C" void kernel_launch(void* const* d_in, const int* in_sizes, int n_in,
                              void* d_out, int out_size, void* d_ws, size_t ws_size,
                              hipStream_t stream) {
    const float* x   = (const float*)d_in[0];
    const int*   wq  = (const int*)d_in[1];
    const float* wos = (const float*)d_in[2];
    const float* wis = (const float*)d_in[3];
    float* out = (float*)d_out;

    short* xb = (short*)d_ws;                                        // 64 MB
    short* wb = (short*)((char*)d_ws + (size_t)M_DIM * K_DIM * 2);   // 128 MB

    cast_x_kernel<<<(M_DIM * (size_t)K_DIM / 8) / 256, 256, 0, stream>>>(x, xb);
    dequant_w_kernel<<<(N_DIM * (size_t)K_DIM / 16) / 256, 256, 0, stream>>>(wq, wos, wis, wb);
    gemm_bt_kernel<<<(M_DIM / BM) * (N_DIM / BN), 512, 0, stream>>>(xb, wb, out);
}